// Round 8
// baseline (5954.898 us; speedup 1.0000x reference)
//
#include <hip/hip_runtime.h>
#include <math.h>

#define NIMG 4
#define CIN 1024
#define CMID 512
#define HGT 64
#define WID 64
#define NA 9
#define NPOS 36864   /* 64*64*9 */
#define PRE 2000
#define POST 300
#define CBLK 4
#define KSPLIT 2
#define KHALF 512    /* CIN / KSPLIT */

#define LOCOFF   0
#define SCOREOFF 589824
#define ROISOFF  884736
#define RIDXOFF  889536
#define ANCHOFF  890736

typedef __attribute__((address_space(1))) const void glob_cv;
typedef __attribute__((address_space(3))) void lds_v;

// ---------------------------------------------------------------------------
// weight transpose: w[cout][cin*9+tap] -> wt32 blocked fp32:
// wt32[(cout/32)][r = cin*9+tap][cout%32], each coutgrp slab contiguous.
// LDS-tiled 64x64. grid (144, 8), 256 thr.
// ---------------------------------------------------------------------------
__global__ __launch_bounds__(256) void wtrans_kernel(
    const float* __restrict__ w, float* __restrict__ wt32)
{
    __shared__ float ts[64][65];
    const int t = threadIdx.x;
    const int rt0 = blockIdx.x * 64;   // r = cin*9+tap dimension (9216)
    const int ct0 = blockIdx.y * 64;   // cout dimension (512)
    const int j = t & 63;
    const int i0 = t >> 6;
#pragma unroll
    for (int k = 0; k < 16; ++k) {
        int i = i0 + k * 4;            // cout-local
        ts[i][j] = w[(size_t)(ct0 + i) * (CIN * 9) + rt0 + j];
    }
    __syncthreads();
    const int cout = ct0 + j;
    const size_t blk = (size_t)(cout >> 5) * (9216 * 32) + (cout & 31);
#pragma unroll
    for (int k = 0; k < 16; ++k) {
        int jj = i0 + k * 4;           // r-local
        wt32[blk + (size_t)(rt0 + jj) * 32] = ts[j][jj];
    }
}

// ---------------------------------------------------------------------------
// conv1 split-K half: 3x3, 512 cins -> raw fp64 partial sums (no bias/relu).
// FMA order within each half = (cin asc, dy, dx, i, c); fp32->fp64 cvt is
// exact, so operand values are bit-identical to the verified R7 kernel ->
// hbuf bit-identical -> rois bit-identical.
// Single-barrier double-buffered global_load_lds pipeline, CBLK=4, 128 stages.
// All DMA address math precomputed (static-unrolled tables, per-stage stride
// advance).  X fp32 [2][4][6][64], W fp32 [2][4*9*32]; LDS 21.5 KB.
// grid (16 rowgrp, 16 coutgrp, img*2+half) = 2048 blocks, 4 blocks/CU.
// ---------------------------------------------------------------------------
__global__ __launch_bounds__(256, 4) void conv1_kernel(
    const float* __restrict__ x, const float* __restrict__ wt32,
    double* __restrict__ hbuf)
{
    __shared__ __align__(16) float Xl[2][CBLK][6][64];
    __shared__ __align__(16) float Wl[2][CBLK * 9 * 32];
    const int t = threadIdx.x;
    const int rowgrp = blockIdx.x, coutgrp = blockIdx.y;
    const int img = blockIdx.z >> 1, half = blockIdx.z & 1;
    const int y0 = rowgrp * 4, c0 = coutgrp * 32;
    const int pg = t & 7, cg = (t >> 3) & 7, rowi = t >> 6;
    const int p0 = pg * 8, cc0 = cg * 4;
    const int lane = t & 63;
    const int cin0 = half * KHALF;

    // edge-row LDS slots are never DMA-written; zero them once (both bufs)
    if (rowgrp == 0) {
        for (int i = t; i < 2 * CBLK * 64; i += 256) {
            int b = i / (CBLK * 64), rem = i % (CBLK * 64);
            Xl[b][rem >> 6][0][rem & 63] = 0.f;
        }
    }
    if (rowgrp == 15) {
        for (int i = t; i < 2 * CBLK * 64; i += 256) {
            int b = i / (CBLK * 64), rem = i % (CBLK * 64);
            Xl[b][rem >> 6][5][rem & 63] = 0.f;
        }
    }

    const int rlo = (rowgrp == 0) ? 1 : 0;
    const int rhi = (rowgrp == 15) ? 4 : 5;
    const int nrows = rhi - rlo + 1;

    // ---- precomputed per-wave DMA issue tables (setup-only div/mod) ----
    const float* xp[6];
    int xoff[6];
    bool xv[6];
#pragma unroll
    for (int j = 0; j < 6; ++j) {
        int k = rowi + j * 4;
        bool v = k < CBLK * nrows;
        int kk = v ? k : 0;
        int cl = kk / nrows, row = rlo + kk % nrows;
        int gr = y0 - 1 + row;
        xp[j] = &x[(((size_t)img * CIN + cin0 + cl) * HGT + gr) * WID] + lane;
        xoff[j] = (cl * 6 + row) * 64;
        xv[j] = v;
    }
    const float* wslab = wt32 + (size_t)coutgrp * (9216 * 32)
                       + (size_t)cin0 * (9 * 32);
    const float* wpA = wslab + rowi * 256 + lane * 4;   // width-16 slot
    const float* wpB = wslab + 1024 + rowi * 64 + lane; // width-4 slot (rowi<2)
    const int woffA = rowi * 256;
    const int woffB = 1024 + rowi * 64;
    const bool wBv = (rowi < 2);

    float* const xb0 = &Xl[0][0][0][0];
    float* const xb1 = &Xl[1][0][0][0];
    float* const wb0 = &Wl[0][0];
    float* const wb1 = &Wl[1][0];

#define ISSUE(NB)                                                          \
    {                                                                      \
        float* xbb = (NB) ? xb1 : xb0;                                     \
        float* wbb = (NB) ? wb1 : wb0;                                     \
        _Pragma("unroll")                                                  \
        for (int j = 0; j < 6; ++j)                                        \
            if (xv[j]) {                                                   \
                __builtin_amdgcn_global_load_lds((glob_cv*)xp[j],          \
                    (lds_v*)(xbb + xoff[j]), 4, 0, 0);                     \
                xp[j] += CBLK * HGT * WID;                                 \
            }                                                              \
        __builtin_amdgcn_global_load_lds((glob_cv*)wpA,                    \
            (lds_v*)(wbb + woffA), 16, 0, 0);                              \
        wpA += CBLK * 9 * 32;                                              \
        if (wBv) {                                                         \
            __builtin_amdgcn_global_load_lds((glob_cv*)wpB,                \
                (lds_v*)(wbb + woffB), 4, 0, 0);                           \
            wpB += CBLK * 9 * 32;                                          \
        }                                                                  \
    }

    double acc[8][4];
#pragma unroll
    for (int i = 0; i < 8; ++i)
#pragma unroll
        for (int c = 0; c < 4; ++c) acc[i][c] = 0.0;

    ISSUE(0)   // prologue: stage 0 -> buf 0

#pragma unroll 1
    for (int s = 0; s < KHALF / CBLK; ++s) {
        const int buf = s & 1;
        __syncthreads();                 // implicit vmcnt(0): stage-s DMA done
        if (s < KHALF / CBLK - 1) ISSUE(buf ^ 1)

        const float* xlb = buf ? xb1 : xb0;
        const float* wlb = buf ? wb1 : wb0;
#pragma unroll 1
        for (int cl = 0; cl < CBLK; ++cl) {
#pragma unroll
            for (int dy = 0; dy < 3; ++dy) {
                const float* xr = xlb + (cl * 6 + rowi + dy) * 64;
                float f0 = (pg != 0) ? xr[p0 - 1] : 0.f;
                float4 xa = *(const float4*)(xr + p0);
                float4 xb = *(const float4*)(xr + p0 + 4);
                float f9 = (pg != 7) ? xr[p0 + 8] : 0.f;
                double xd[10];
                xd[0] = (double)f0;
                xd[1] = (double)xa.x; xd[2] = (double)xa.y;
                xd[3] = (double)xa.z; xd[4] = (double)xa.w;
                xd[5] = (double)xb.x; xd[6] = (double)xb.y;
                xd[7] = (double)xb.z; xd[8] = (double)xb.w;
                xd[9] = (double)f9;
#pragma unroll
                for (int dx = 0; dx < 3; ++dx) {
                    const float* wp = wlb + (cl * 9 + dy * 3 + dx) * 32 + cc0;
                    float4 wv = *(const float4*)wp;
                    double w0 = (double)wv.x, w1 = (double)wv.y;
                    double w2 = (double)wv.z, w3 = (double)wv.w;
#pragma unroll
                    for (int i = 0; i < 8; ++i) {
                        double xv2 = xd[i + dx];
                        acc[i][0] += xv2 * w0;
                        acc[i][1] += xv2 * w1;
                        acc[i][2] += xv2 * w2;
                        acc[i][3] += xv2 * w3;
                    }
                }
            }
        }
    }

    // epilogue: store raw fp64 partials (bias/relu/cast applied at combine)
#pragma unroll
    for (int co = 0; co < 4; ++co) {
        double* dst = &hbuf[(((size_t)(half * NIMG + img) * CMID + c0 + cc0 + co)
                             * 4096) + (size_t)(y0 + rowi) * 64 + p0];
#pragma unroll
        for (int i = 0; i < 8; i += 2)
            *(double2*)(dst + i) = make_double2(acc[i][co], acc[i + 1][co]);
    }
#undef ISSUE
}

// ---------------------------------------------------------------------------
// 1x1 convs (loc 36ch + score 18ch fused, padded to 56 = 4 groups of 14).
// Combines the two conv1 K-halves on the fly:
//   mid = (double)(float)relu(h1 + h2 + bias)   [matches fp32 mid roundtrip]
// fp64 accumulate. Writes rpn_locs/rpn_scores fp32 to d_out, loc fp64 and
// score-diff key fp64 to workspace.  grid (16 pixblk, 4 grp, 4 img), 256 thr
// ---------------------------------------------------------------------------
__global__ __launch_bounds__(256) void conv1x1_kernel(
    const double* __restrict__ hbuf, const float* __restrict__ c1b,
    const float* __restrict__ sw, const float* __restrict__ sb,
    const float* __restrict__ lw, const float* __restrict__ lb,
    float* __restrict__ out, double* __restrict__ locws, double* __restrict__ keyws)
{
    const int t = threadIdx.x;
    const int p = blockIdx.x * 256 + t;       // pixel 0..4095
    const int g = blockIdx.y;                 // channel group
    const int img = blockIdx.z;

    double acc[14];
#pragma unroll
    for (int k = 0; k < 14; ++k) acc[k] = 0.0;

    const double* h1 = hbuf + (size_t)img * CMID * 4096 + p;
    const double* h2 = hbuf + (size_t)(NIMG + img) * CMID * 4096 + p;
    for (int cin = 0; cin < CMID; ++cin) {
        double m = h1[(size_t)cin * 4096] + h2[(size_t)cin * 4096]
                   + (double)c1b[cin];
        m = m > 0.0 ? m : 0.0;
        double xd = (double)(float)m;          // fp32 mid roundtrip
#pragma unroll
        for (int k = 0; k < 14; ++k) {
            int c = g * 14 + k;
            double wv = 0.0;
            if (c < 36)      wv = (double)lw[c * CMID + cin];
            else if (c < 54) wv = (double)sw[(c - 36) * CMID + cin];
            acc[k] += xd * wv;
        }
    }

    double prev = 0.0;
#pragma unroll
    for (int k = 0; k < 14; ++k) {
        int c = g * 14 + k;
        if (c >= 54) continue;
        if (c < 36) {
            double v = acc[k] + (double)lb[c];
            int a = c >> 2, cc = c & 3;
            size_t ix = (size_t)img * NPOS + (size_t)p * NA + a;
            locws[ix * 4 + cc] = v;
            out[LOCOFF + ix * 4 + cc] = (float)v;
        } else {
            int sc = c - 36;
            double v = acc[k] + (double)sb[sc];
            int a = sc >> 1;
            size_t ix = (size_t)img * NPOS + (size_t)p * NA + a;
            out[SCOREOFF + ix * 2 + (sc & 1)] = (float)v;
            if (sc & 1) keyws[ix] = v - prev;   // s1 - s0 (fg rank key, fp64)
            prev = v;
        }
    }
}

// ---------------------------------------------------------------------------
// boxes: anchors + loc2bbox + clip + min-size gate (fp64); histogram of keys.
// grid (144, 4 img), 256 thr
// ---------------------------------------------------------------------------
__device__ __forceinline__ unsigned mono_of(double k) {
    unsigned fb = __float_as_uint((float)k);
    return (fb & 0x80000000u) ? ~fb : (fb | 0x80000000u);
}

__global__ __launch_bounds__(256) void boxes_kernel(
    double* __restrict__ keyio, const double* __restrict__ locws,
    const int* __restrict__ imh, const int* __restrict__ imw,
    float* __restrict__ out, double* __restrict__ boxes, unsigned* __restrict__ hist)
{
    __shared__ unsigned lh[4096];
    const int t = threadIdx.x;
    const int img = blockIdx.y;
    const int pos = blockIdx.x * 256 + t;
    for (int i = t; i < 4096; i += 256) lh[i] = 0;
    __syncthreads();

    int a = pos % 9, hw = pos / 9;
    int hy = hw >> 6, hx = hw & 63;
    int r_idx = a / 3, s_idx = a % 3;
    double ratio = r_idx == 0 ? 0.5 : (r_idx == 1 ? 1.0 : 2.0);
    double scl   = s_idx == 0 ? 8.0 : (s_idx == 1 ? 16.0 : 32.0);
    double hh2 = 8.0 * scl * sqrt(ratio);
    double ww2 = 8.0 * scl * sqrt(1.0 / ratio);
    float ay1 = (float)(8.0 - hh2), ax1 = (float)(8.0 - ww2);
    float ay2 = (float)(8.0 + hh2), ax2 = (float)(8.0 + ww2);
    float sy = (float)(hy * 16), sx = (float)(hx * 16);
    float A0 = sy + ay1, A1 = sx + ax1, A2 = sy + ay2, A3 = sx + ax2;
    if (img == 0) {
        size_t ao = ANCHOFF + (size_t)pos * 4;
        out[ao + 0] = A0; out[ao + 1] = A1; out[ao + 2] = A2; out[ao + 3] = A3;
    }

    size_t ix = (size_t)img * NPOS + pos;
    const double* lp = &locws[ix * 4];
    double h = (double)A2 - (double)A0, w_ = (double)A3 - (double)A1;
    double cy = (double)A0 + 0.5 * h, cx = (double)A1 + 0.5 * w_;
    double dy = lp[0], dx = lp[1], dh = lp[2], dw = lp[3];
    double ncy = dy * h + cy, ncx = dx * w_ + cx;
    double nh = exp(dh) * h, nw = exp(dw) * w_;
    double Hc = (double)imh[0], Wc = (double)imw[0];
    double y1 = ncy - 0.5 * nh, x1 = ncx - 0.5 * nw;
    double y2 = ncy + 0.5 * nh, x2 = ncx + 0.5 * nw;
    y1 = fmin(fmax(y1, 0.0), Hc); x1 = fmin(fmax(x1, 0.0), Wc);
    y2 = fmin(fmax(y2, 0.0), Hc); x2 = fmin(fmax(x2, 0.0), Wc);
    boxes[ix * 4 + 0] = y1; boxes[ix * 4 + 1] = x1;
    boxes[ix * 4 + 2] = y2; boxes[ix * 4 + 3] = x2;

    bool valid = ((y2 - y1) >= 16.0) && ((x2 - x1) >= 16.0);
    double kg = valid ? keyio[ix] : -INFINITY;
    keyio[ix] = kg;
    atomicAdd(&lh[mono_of(kg) >> 20], 1u);
    __syncthreads();
    for (int i = t; i < 4096; i += 256)
        if (lh[i]) atomicAdd(&hist[img * 4096 + i], lh[i]);
}

// grid 4 blocks x 64 thr (thread 0 works): find cutoff bin for >= PRE cands
__global__ void cutoff_kernel(const unsigned* __restrict__ hist, int* __restrict__ cutoffb)
{
    if (threadIdx.x) return;
    int img = blockIdx.x;
    unsigned cum = 0; int cb = 0;
    for (int b = 4095; b >= 0; --b) {
        cum += hist[img * 4096 + b];
        if (cum >= PRE) { cb = b; break; }
    }
    cutoffb[img] = cb;
}

// grid (144, 4): compact candidates with bin >= cutoff
__global__ __launch_bounds__(256) void compact_kernel(
    const double* __restrict__ keyio, const int* __restrict__ cutoffb,
    int* __restrict__ candCnt, int* __restrict__ candIdx, double* __restrict__ candKey)
{
    int img = blockIdx.y;
    int pos = blockIdx.x * 256 + threadIdx.x;
    size_t ix = (size_t)img * NPOS + pos;
    double k = keyio[ix];
    if ((int)(mono_of(k) >> 20) >= cutoffb[img]) {
        int p = atomicAdd(&candCnt[img], 1);
        candIdx[img * NPOS + p] = pos;
        candKey[(size_t)img * NPOS + p] = k;
    }
}

// grid (144, 4): exact rank (desc value, asc index) among candidates -> top-2000
__global__ __launch_bounds__(256) void rank_kernel(
    const int* __restrict__ candCnt, const int* __restrict__ candIdx,
    const double* __restrict__ candKey, const double* __restrict__ boxes,
    int* __restrict__ topIdx, int* __restrict__ topValid, double* __restrict__ bsel)
{
    __shared__ double sk[256];
    __shared__ int si[256];
    int img = blockIdx.y, t = threadIdx.x;
    int M = candCnt[img];
    if (blockIdx.x * 256 >= M) return;   // uniform per block
    int i = blockIdx.x * 256 + t;
    bool act = i < M;
    double ki = 0.0; int pi = 0;
    if (act) { ki = candKey[(size_t)img * NPOS + i]; pi = candIdx[img * NPOS + i]; }
    int rank = 0;
    for (int jb = 0; jb < M; jb += 256) {
        int j = jb + t;
        if (j < M) { sk[t] = candKey[(size_t)img * NPOS + j]; si[t] = candIdx[img * NPOS + j]; }
        __syncthreads();
        int lim = min(256, M - jb);
        if (act) {
            for (int jj = 0; jj < lim; ++jj) {
                double kj = sk[jj]; int pj = si[jj];
                rank += (kj > ki || (kj == ki && pj < pi)) ? 1 : 0;
            }
        }
        __syncthreads();
    }
    if (act && rank < PRE) {
        topIdx[img * PRE + rank] = pi;
        topValid[img * PRE + rank] = (ki != -INFINITY) ? 1 : 0;
        const double* bp = &boxes[((size_t)img * NPOS + pi) * 4];
        double* bs = &bsel[((size_t)img * PRE + rank) * 4];
        bs[0] = bp[0]; bs[1] = bp[1]; bs[2] = bp[2]; bs[3] = bp[3];
    }
}

// grid (2000, 4): per-row suppression bitmask (j > i, iou > 0.7)
__global__ __launch_bounds__(256) void mask_kernel(
    const double* __restrict__ bsel, unsigned long long* __restrict__ mask)
{
    int i = blockIdx.x, img = blockIdx.y, t = threadIdx.x;
    const double* bi = &bsel[((size_t)img * PRE + i) * 4];
    double y1i = bi[0], x1i = bi[1], y2i = bi[2], x2i = bi[3];
    double ai = (y2i - y1i) * (x2i - x1i);
#pragma unroll 1
    for (int it = 0; it < 8; ++it) {
        int j = it * 256 + t;
        bool pred = false;
        if (j < PRE && j > i) {
            const double* bj = &bsel[((size_t)img * PRE + j) * 4];
            double ty = fmax(y1i, bj[0]), tx = fmax(x1i, bj[1]);
            double by = fmin(y2i, bj[2]), bx = fmin(x2i, bj[3]);
            double inter = fmax(by - ty, 0.0) * fmax(bx - tx, 0.0);
            double aj = (bj[2] - bj[0]) * (bj[3] - bj[1]);
            double iou = inter / (ai + aj - inter);
            pred = iou > 0.7;
        }
        unsigned long long m = __ballot(pred);
        if ((t & 63) == 0)
            mask[((size_t)img * PRE + i) * 32 + it * 4 + (t >> 6)] = m;
    }
}

// grid 4 x 64 thr (1 wave): sequential greedy NMS over 2000 with bitmask words
__global__ void nms_kernel(const unsigned long long* __restrict__ mask,
                           const int* __restrict__ topValid, int* __restrict__ keepA)
{
    int img = blockIdx.x, lane = threadIdx.x;
    size_t base = (size_t)img * PRE;
    unsigned long long remv = 0;
    if (lane < 32) {
        unsigned long long tv = 0;
        for (int b = 0; b < 64; ++b) {
            int idx = lane * 64 + b;
            if (idx < PRE && topValid[base + idx]) tv |= (1ull << b);
        }
        remv = ~tv;   // invalid (-inf) entries pre-suppressed
    }
    const unsigned long long* mrow = &mask[base * 32];
    unsigned long long c0 = 0, c1 = 0, c2 = 0, c3 = 0;
    if (lane < 32) {
        c0 = mrow[(size_t)0 * 32 + lane]; c1 = mrow[(size_t)1 * 32 + lane];
        c2 = mrow[(size_t)2 * 32 + lane]; c3 = mrow[(size_t)3 * 32 + lane];
    }
    for (int i = 0; i < PRE; i += 4) {
        unsigned long long n0 = 0, n1 = 0, n2 = 0, n3 = 0;
        if (lane < 32 && i + 4 < PRE) {
            n0 = mrow[(size_t)(i + 4) * 32 + lane];
            n1 = mrow[(size_t)(i + 5) * 32 + lane];
            n2 = mrow[(size_t)(i + 6) * 32 + lane];
            n3 = mrow[(size_t)(i + 7) * 32 + lane];
        }
        {
            unsigned long long rw = __shfl(remv, i >> 6);
            int kp = !((rw >> (i & 63)) & 1ull);
            if (lane == 0) keepA[base + i] = kp;
            if (kp) remv |= c0;
        }
        {
            int ii = i + 1;
            unsigned long long rw = __shfl(remv, ii >> 6);
            int kp = !((rw >> (ii & 63)) & 1ull);
            if (lane == 0) keepA[base + ii] = kp;
            if (kp) remv |= c1;
        }
        {
            int ii = i + 2;
            unsigned long long rw = __shfl(remv, ii >> 6);
            int kp = !((rw >> (ii & 63)) & 1ull);
            if (lane == 0) keepA[base + ii] = kp;
            if (kp) remv |= c2;
        }
        {
            int ii = i + 3;
            unsigned long long rw = __shfl(remv, ii >> 6);
            int kp = !((rw >> (ii & 63)) & 1ull);
            if (lane == 0) keepA[base + ii] = kp;
            if (kp) remv |= c3;
        }
        c0 = n0; c1 = n1; c2 = n2; c3 = n3;
    }
}

// grid 4 x 256: prefix-scan keep -> emit first 300 kept rois, zero the rest
__global__ __launch_bounds__(256) void final_kernel(
    const int* __restrict__ keepA, const double* __restrict__ bsel, float* __restrict__ out)
{
    __shared__ int ssum[256];
    __shared__ int stot;
    int img = blockIdx.x, t = threadIdx.x;
    size_t base = (size_t)img * PRE;
    int loc[8]; int s = 0;
#pragma unroll
    for (int k = 0; k < 8; ++k) {
        int i = t * 8 + k;
        loc[k] = (i < PRE) ? keepA[base + i] : 0;
        s += loc[k];
    }
    ssum[t] = s;
    __syncthreads();
    if (t == 0) {
        int run = 0;
        for (int u = 0; u < 256; ++u) { int tmp = ssum[u]; ssum[u] = run; run += tmp; }
        stot = run;
    }
    __syncthreads();
    int run = ssum[t];
#pragma unroll
    for (int k = 0; k < 8; ++k) {
        int i = t * 8 + k;
        if (i < PRE && loc[k]) {
            int p = run++;
            if (p < POST) {
                const double* bp = &bsel[(base + i) * 4];
                size_t ro = ROISOFF + ((size_t)img * POST + p) * 4;
                out[ro + 0] = (float)bp[0]; out[ro + 1] = (float)bp[1];
                out[ro + 2] = (float)bp[2]; out[ro + 3] = (float)bp[3];
                out[RIDXOFF + img * POST + p] = (float)img;
            }
        }
    }
    __syncthreads();
    int nk = stot;
    for (int r = t; r < POST; r += 256) {
        if (r >= nk) {
            size_t ro = ROISOFF + ((size_t)img * POST + r) * 4;
            out[ro + 0] = 0.f; out[ro + 1] = 0.f; out[ro + 2] = 0.f; out[ro + 3] = 0.f;
            out[RIDXOFF + img * POST + r] = -1.f;
        }
    }
}

// ---------------------------------------------------------------------------
extern "C" void kernel_launch(void* const* d_in, const int* in_sizes, int n_in,
                              void* d_out, int out_size, void* d_ws, size_t ws_size,
                              hipStream_t stream)
{
    const float* x   = (const float*)d_in[0];
    const float* c1w = (const float*)d_in[1];
    const float* c1b = (const float*)d_in[2];
    const float* sw  = (const float*)d_in[3];
    const float* sb  = (const float*)d_in[4];
    const float* lw  = (const float*)d_in[5];
    const float* lb  = (const float*)d_in[6];
    const int*   ih  = (const int*)d_in[7];
    const int*   iw  = (const int*)d_in[8];
    float* out = (float*)d_out;
    (void)in_sizes; (void)n_in; (void)out_size; (void)ws_size;

    char* ws = (char*)d_ws;
    size_t off = 0;
    auto alloc = [&](size_t bytes) -> void* {
        void* p = (void*)(ws + off);
        off = (off + bytes + 255) & ~(size_t)255;
        return p;
    };
    double* hbuf     = (double*)alloc((size_t)KSPLIT * NIMG * CMID * 4096 * 8); // 134 MiB
    float*  wt32     = (float*) alloc((size_t)CMID * CIN * 9 * 4);              // 18.9 MiB
    double* locws    = (double*)alloc((size_t)NIMG * NPOS * 4 * 8);
    double* keyws    = (double*)alloc((size_t)NIMG * NPOS * 8);
    double* boxes    = (double*)alloc((size_t)NIMG * NPOS * 4 * 8);
    unsigned* hist   = (unsigned*)alloc((size_t)NIMG * 4096 * 4);
    int*    cutoffb  = (int*)   alloc(64);
    int*    candCnt  = (int*)   alloc(64);
    int*    candIdx  = (int*)   alloc((size_t)NIMG * NPOS * 4);
    double* candKey  = (double*)alloc((size_t)NIMG * NPOS * 8);
    int*    topIdx   = (int*)   alloc((size_t)NIMG * PRE * 4);
    int*    topValid = (int*)   alloc((size_t)NIMG * PRE * 4);
    double* bsel     = (double*)alloc((size_t)NIMG * PRE * 4 * 8);
    unsigned long long* mask = (unsigned long long*)alloc((size_t)NIMG * PRE * 32 * 8);
    int*    keepA    = (int*)   alloc((size_t)NIMG * PRE * 4);

    hipMemsetAsync(hist, 0, (size_t)NIMG * 4096 * 4, stream);
    hipMemsetAsync(candCnt, 0, 64, stream);

    wtrans_kernel <<<dim3(144, 8),                256, 0, stream>>>(c1w, wt32);
    conv1_kernel  <<<dim3(16, 16, NIMG * KSPLIT), 256, 0, stream>>>(x, wt32, hbuf);
    conv1x1_kernel<<<dim3(16, 4, NIMG),           256, 0, stream>>>(hbuf, c1b, sw, sb, lw, lb,
                                                                    out, locws, keyws);
    boxes_kernel  <<<dim3(144, NIMG),             256, 0, stream>>>(keyws, locws, ih, iw, out, boxes, hist);
    cutoff_kernel <<<NIMG, 64, 0, stream>>>(hist, cutoffb);
    compact_kernel<<<dim3(144, NIMG),             256, 0, stream>>>(keyws, cutoffb, candCnt, candIdx, candKey);
    rank_kernel   <<<dim3(144, NIMG),             256, 0, stream>>>(candCnt, candIdx, candKey, boxes,
                                                                    topIdx, topValid, bsel);
    mask_kernel   <<<dim3(PRE, NIMG),             256, 0, stream>>>(bsel, mask);
    nms_kernel    <<<NIMG, 64, 0, stream>>>(mask, topValid, keepA);
    final_kernel  <<<NIMG, 256, 0, stream>>>(keepA, bsel, out);
}

// Round 9
// 4307.148 us; speedup vs baseline: 1.3826x; 1.3826x over previous
//
#include <hip/hip_runtime.h>
#include <math.h>

#define NIMG 4
#define CIN 1024
#define CMID 512
#define HGT 64
#define WID 64
#define NA 9
#define NPOS 36864   /* 64*64*9 */
#define PRE 2000
#define POST 300
#define CBLK 4
#define KSPLIT 2
#define KHALF 512    /* CIN / KSPLIT */

#define LOCOFF   0
#define SCOREOFF 589824
#define ROISOFF  884736
#define RIDXOFF  889536
#define ANCHOFF  890736

typedef __attribute__((address_space(1))) const void glob_cv;
typedef __attribute__((address_space(3))) void lds_v;

// ---------------------------------------------------------------------------
// weight transpose: w[cout][cin*9+tap] -> wt32 blocked fp32:
// wt32[(cout/32)][r = cin*9+tap][cout%32], each coutgrp slab contiguous.
// LDS-tiled 64x64. grid (144, 8), 256 thr.
// ---------------------------------------------------------------------------
__global__ __launch_bounds__(256) void wtrans_kernel(
    const float* __restrict__ w, float* __restrict__ wt32)
{
    __shared__ float ts[64][65];
    const int t = threadIdx.x;
    const int rt0 = blockIdx.x * 64;   // r = cin*9+tap dimension (9216)
    const int ct0 = blockIdx.y * 64;   // cout dimension (512)
    const int j = t & 63;
    const int i0 = t >> 6;
#pragma unroll
    for (int k = 0; k < 16; ++k) {
        int i = i0 + k * 4;            // cout-local
        ts[i][j] = w[(size_t)(ct0 + i) * (CIN * 9) + rt0 + j];
    }
    __syncthreads();
    const int cout = ct0 + j;
    const size_t blk = (size_t)(cout >> 5) * (9216 * 32) + (cout & 31);
#pragma unroll
    for (int k = 0; k < 16; ++k) {
        int jj = i0 + k * 4;           // r-local
        wt32[blk + (size_t)(rt0 + jj) * 32] = ts[j][jj];
    }
}

// ---------------------------------------------------------------------------
// conv1 split-K half: 3x3, 512 cins -> raw fp64 partial sums (no bias/relu).
// FMA order within each half = (cin asc, dy, dx, i, c); fp32->fp64 cvt is
// exact, so operand values are bit-identical to the verified R7 kernel ->
// hbuf bit-identical -> rois bit-identical.
// Single-barrier double-buffered global_load_lds pipeline, CBLK=4, 128 stages.
// All DMA address math precomputed.  X fp32 [2][4][6][64], W fp32
// [2][4*9*32]; LDS 21.5 KB.  __launch_bounds__(256,2): 128-VGPR cap, kernel
// fits (~100) with ZERO spill (R8's (256,4)=64-VGPR cap spilled 8.9 GB).
// grid (16 rowgrp, 16 coutgrp, img*2+half) = 2048 blocks.
// ---------------------------------------------------------------------------
__global__ __launch_bounds__(256, 2) void conv1_kernel(
    const float* __restrict__ x, const float* __restrict__ wt32,
    double* __restrict__ hbuf)
{
    __shared__ __align__(16) float Xl[2][CBLK][6][64];
    __shared__ __align__(16) float Wl[2][CBLK * 9 * 32];
    const int t = threadIdx.x;
    const int rowgrp = blockIdx.x, coutgrp = blockIdx.y;
    const int img = blockIdx.z >> 1, half = blockIdx.z & 1;
    const int y0 = rowgrp * 4, c0 = coutgrp * 32;
    const int pg = t & 7, cg = (t >> 3) & 7, rowi = t >> 6;
    const int p0 = pg * 8, cc0 = cg * 4;
    const int lane = t & 63;
    const int cin0 = half * KHALF;

    // edge-row LDS slots are never DMA-written; zero them once (both bufs)
    if (rowgrp == 0) {
        for (int i = t; i < 2 * CBLK * 64; i += 256) {
            int b = i / (CBLK * 64), rem = i % (CBLK * 64);
            Xl[b][rem >> 6][0][rem & 63] = 0.f;
        }
    }
    if (rowgrp == 15) {
        for (int i = t; i < 2 * CBLK * 64; i += 256) {
            int b = i / (CBLK * 64), rem = i % (CBLK * 64);
            Xl[b][rem >> 6][5][rem & 63] = 0.f;
        }
    }

    const int rlo = (rowgrp == 0) ? 1 : 0;
    const int rhi = (rowgrp == 15) ? 4 : 5;
    const int nrows = rhi - rlo + 1;

    // ---- precomputed per-wave DMA issue tables (setup-only div/mod) ----
    const float* xp[6];
    int xoff[6];
    bool xv[6];
#pragma unroll
    for (int j = 0; j < 6; ++j) {
        int k = rowi + j * 4;
        bool v = k < CBLK * nrows;
        int kk = v ? k : 0;
        int cl = kk / nrows, row = rlo + kk % nrows;
        int gr = y0 - 1 + row;
        xp[j] = &x[(((size_t)img * CIN + cin0 + cl) * HGT + gr) * WID] + lane;
        xoff[j] = (cl * 6 + row) * 64;
        xv[j] = v;
    }
    const float* wslab = wt32 + (size_t)coutgrp * (9216 * 32)
                       + (size_t)cin0 * (9 * 32);
    const float* wpA = wslab + rowi * 256 + lane * 4;   // width-16 slot
    const float* wpB = wslab + 1024 + rowi * 64 + lane; // width-4 slot (rowi<2)
    const int woffA = rowi * 256;
    const int woffB = 1024 + rowi * 64;
    const bool wBv = (rowi < 2);

    float* const xb0 = &Xl[0][0][0][0];
    float* const xb1 = &Xl[1][0][0][0];
    float* const wb0 = &Wl[0][0];
    float* const wb1 = &Wl[1][0];

#define ISSUE(NB)                                                          \
    {                                                                      \
        float* xbb = (NB) ? xb1 : xb0;                                     \
        float* wbb = (NB) ? wb1 : wb0;                                     \
        _Pragma("unroll")                                                  \
        for (int j = 0; j < 6; ++j)                                        \
            if (xv[j]) {                                                   \
                __builtin_amdgcn_global_load_lds((glob_cv*)xp[j],          \
                    (lds_v*)(xbb + xoff[j]), 4, 0, 0);                     \
                xp[j] += CBLK * HGT * WID;                                 \
            }                                                              \
        __builtin_amdgcn_global_load_lds((glob_cv*)wpA,                    \
            (lds_v*)(wbb + woffA), 16, 0, 0);                              \
        wpA += CBLK * 9 * 32;                                              \
        if (wBv) {                                                         \
            __builtin_amdgcn_global_load_lds((glob_cv*)wpB,                \
                (lds_v*)(wbb + woffB), 4, 0, 0);                           \
            wpB += CBLK * 9 * 32;                                          \
        }                                                                  \
    }

    double acc[8][4];
#pragma unroll
    for (int i = 0; i < 8; ++i)
#pragma unroll
        for (int c = 0; c < 4; ++c) acc[i][c] = 0.0;

    ISSUE(0)   // prologue: stage 0 -> buf 0

#pragma unroll 1
    for (int s = 0; s < KHALF / CBLK; ++s) {
        const int buf = s & 1;
        __syncthreads();                 // implicit vmcnt(0): stage-s DMA done
        if (s < KHALF / CBLK - 1) ISSUE(buf ^ 1)

        const float* xlb = buf ? xb1 : xb0;
        const float* wlb = buf ? wb1 : wb0;
#pragma unroll 1
        for (int cl = 0; cl < CBLK; ++cl) {
#pragma unroll
            for (int dy = 0; dy < 3; ++dy) {
                const float* xr = xlb + (cl * 6 + rowi + dy) * 64;
                float f0 = (pg != 0) ? xr[p0 - 1] : 0.f;
                float4 xa = *(const float4*)(xr + p0);
                float4 xb = *(const float4*)(xr + p0 + 4);
                float f9 = (pg != 7) ? xr[p0 + 8] : 0.f;
                double xd[10];
                xd[0] = (double)f0;
                xd[1] = (double)xa.x; xd[2] = (double)xa.y;
                xd[3] = (double)xa.z; xd[4] = (double)xa.w;
                xd[5] = (double)xb.x; xd[6] = (double)xb.y;
                xd[7] = (double)xb.z; xd[8] = (double)xb.w;
                xd[9] = (double)f9;
#pragma unroll
                for (int dx = 0; dx < 3; ++dx) {
                    const float* wp = wlb + (cl * 9 + dy * 3 + dx) * 32 + cc0;
                    float4 wv = *(const float4*)wp;
                    double w0 = (double)wv.x, w1 = (double)wv.y;
                    double w2 = (double)wv.z, w3 = (double)wv.w;
#pragma unroll
                    for (int i = 0; i < 8; ++i) {
                        double xv2 = xd[i + dx];
                        acc[i][0] += xv2 * w0;
                        acc[i][1] += xv2 * w1;
                        acc[i][2] += xv2 * w2;
                        acc[i][3] += xv2 * w3;
                    }
                }
            }
        }
    }

    // epilogue: store raw fp64 partials (bias/relu/cast applied at combine)
#pragma unroll
    for (int co = 0; co < 4; ++co) {
        double* dst = &hbuf[(((size_t)(half * NIMG + img) * CMID + c0 + cc0 + co)
                             * 4096) + (size_t)(y0 + rowi) * 64 + p0];
#pragma unroll
        for (int i = 0; i < 8; i += 2)
            *(double2*)(dst + i) = make_double2(acc[i][co], acc[i + 1][co]);
    }
#undef ISSUE
}

// ---------------------------------------------------------------------------
// 1x1 convs (loc 36ch + score 18ch fused, padded to 56 = 4 groups of 14).
// Combines the two conv1 K-halves on the fly:
//   mid = (double)(float)relu(h1 + h2 + bias)   [matches fp32 mid roundtrip]
// fp64 accumulate. Writes rpn_locs/rpn_scores fp32 to d_out, loc fp64 and
// score-diff key fp64 to workspace.  grid (16 pixblk, 4 grp, 4 img), 256 thr
// ---------------------------------------------------------------------------
__global__ __launch_bounds__(256) void conv1x1_kernel(
    const double* __restrict__ hbuf, const float* __restrict__ c1b,
    const float* __restrict__ sw, const float* __restrict__ sb,
    const float* __restrict__ lw, const float* __restrict__ lb,
    float* __restrict__ out, double* __restrict__ locws, double* __restrict__ keyws)
{
    const int t = threadIdx.x;
    const int p = blockIdx.x * 256 + t;       // pixel 0..4095
    const int g = blockIdx.y;                 // channel group
    const int img = blockIdx.z;

    double acc[14];
#pragma unroll
    for (int k = 0; k < 14; ++k) acc[k] = 0.0;

    const double* h1 = hbuf + (size_t)img * CMID * 4096 + p;
    const double* h2 = hbuf + (size_t)(NIMG + img) * CMID * 4096 + p;
    for (int cin = 0; cin < CMID; ++cin) {
        double m = h1[(size_t)cin * 4096] + h2[(size_t)cin * 4096]
                   + (double)c1b[cin];
        m = m > 0.0 ? m : 0.0;
        double xd = (double)(float)m;          // fp32 mid roundtrip
#pragma unroll
        for (int k = 0; k < 14; ++k) {
            int c = g * 14 + k;
            double wv = 0.0;
            if (c < 36)      wv = (double)lw[c * CMID + cin];
            else if (c < 54) wv = (double)sw[(c - 36) * CMID + cin];
            acc[k] += xd * wv;
        }
    }

    double prev = 0.0;
#pragma unroll
    for (int k = 0; k < 14; ++k) {
        int c = g * 14 + k;
        if (c >= 54) continue;
        if (c < 36) {
            double v = acc[k] + (double)lb[c];
            int a = c >> 2, cc = c & 3;
            size_t ix = (size_t)img * NPOS + (size_t)p * NA + a;
            locws[ix * 4 + cc] = v;
            out[LOCOFF + ix * 4 + cc] = (float)v;
        } else {
            int sc = c - 36;
            double v = acc[k] + (double)sb[sc];
            int a = sc >> 1;
            size_t ix = (size_t)img * NPOS + (size_t)p * NA + a;
            out[SCOREOFF + ix * 2 + (sc & 1)] = (float)v;
            if (sc & 1) keyws[ix] = v - prev;   // s1 - s0 (fg rank key, fp64)
            prev = v;
        }
    }
}

// ---------------------------------------------------------------------------
// boxes: anchors + loc2bbox + clip + min-size gate (fp64); histogram of keys.
// grid (144, 4 img), 256 thr
// ---------------------------------------------------------------------------
__device__ __forceinline__ unsigned mono_of(double k) {
    unsigned fb = __float_as_uint((float)k);
    return (fb & 0x80000000u) ? ~fb : (fb | 0x80000000u);
}

__global__ __launch_bounds__(256) void boxes_kernel(
    double* __restrict__ keyio, const double* __restrict__ locws,
    const int* __restrict__ imh, const int* __restrict__ imw,
    float* __restrict__ out, double* __restrict__ boxes, unsigned* __restrict__ hist)
{
    __shared__ unsigned lh[4096];
    const int t = threadIdx.x;
    const int img = blockIdx.y;
    const int pos = blockIdx.x * 256 + t;
    for (int i = t; i < 4096; i += 256) lh[i] = 0;
    __syncthreads();

    int a = pos % 9, hw = pos / 9;
    int hy = hw >> 6, hx = hw & 63;
    int r_idx = a / 3, s_idx = a % 3;
    double ratio = r_idx == 0 ? 0.5 : (r_idx == 1 ? 1.0 : 2.0);
    double scl   = s_idx == 0 ? 8.0 : (s_idx == 1 ? 16.0 : 32.0);
    double hh2 = 8.0 * scl * sqrt(ratio);
    double ww2 = 8.0 * scl * sqrt(1.0 / ratio);
    float ay1 = (float)(8.0 - hh2), ax1 = (float)(8.0 - ww2);
    float ay2 = (float)(8.0 + hh2), ax2 = (float)(8.0 + ww2);
    float sy = (float)(hy * 16), sx = (float)(hx * 16);
    float A0 = sy + ay1, A1 = sx + ax1, A2 = sy + ay2, A3 = sx + ax2;
    if (img == 0) {
        size_t ao = ANCHOFF + (size_t)pos * 4;
        out[ao + 0] = A0; out[ao + 1] = A1; out[ao + 2] = A2; out[ao + 3] = A3;
    }

    size_t ix = (size_t)img * NPOS + pos;
    const double* lp = &locws[ix * 4];
    double h = (double)A2 - (double)A0, w_ = (double)A3 - (double)A1;
    double cy = (double)A0 + 0.5 * h, cx = (double)A1 + 0.5 * w_;
    double dy = lp[0], dx = lp[1], dh = lp[2], dw = lp[3];
    double ncy = dy * h + cy, ncx = dx * w_ + cx;
    double nh = exp(dh) * h, nw = exp(dw) * w_;
    double Hc = (double)imh[0], Wc = (double)imw[0];
    double y1 = ncy - 0.5 * nh, x1 = ncx - 0.5 * nw;
    double y2 = ncy + 0.5 * nh, x2 = ncx + 0.5 * nw;
    y1 = fmin(fmax(y1, 0.0), Hc); x1 = fmin(fmax(x1, 0.0), Wc);
    y2 = fmin(fmax(y2, 0.0), Hc); x2 = fmin(fmax(x2, 0.0), Wc);
    boxes[ix * 4 + 0] = y1; boxes[ix * 4 + 1] = x1;
    boxes[ix * 4 + 2] = y2; boxes[ix * 4 + 3] = x2;

    bool valid = ((y2 - y1) >= 16.0) && ((x2 - x1) >= 16.0);
    double kg = valid ? keyio[ix] : -INFINITY;
    keyio[ix] = kg;
    atomicAdd(&lh[mono_of(kg) >> 20], 1u);
    __syncthreads();
    for (int i = t; i < 4096; i += 256)
        if (lh[i]) atomicAdd(&hist[img * 4096 + i], lh[i]);
}

// grid 4 blocks x 64 thr (thread 0 works): find cutoff bin for >= PRE cands
__global__ void cutoff_kernel(const unsigned* __restrict__ hist, int* __restrict__ cutoffb)
{
    if (threadIdx.x) return;
    int img = blockIdx.x;
    unsigned cum = 0; int cb = 0;
    for (int b = 4095; b >= 0; --b) {
        cum += hist[img * 4096 + b];
        if (cum >= PRE) { cb = b; break; }
    }
    cutoffb[img] = cb;
}

// grid (144, 4): compact candidates with bin >= cutoff
__global__ __launch_bounds__(256) void compact_kernel(
    const double* __restrict__ keyio, const int* __restrict__ cutoffb,
    int* __restrict__ candCnt, int* __restrict__ candIdx, double* __restrict__ candKey)
{
    int img = blockIdx.y;
    int pos = blockIdx.x * 256 + threadIdx.x;
    size_t ix = (size_t)img * NPOS + pos;
    double k = keyio[ix];
    if ((int)(mono_of(k) >> 20) >= cutoffb[img]) {
        int p = atomicAdd(&candCnt[img], 1);
        candIdx[img * NPOS + p] = pos;
        candKey[(size_t)img * NPOS + p] = k;
    }
}

// grid (144, 4): exact rank (desc value, asc index) among candidates -> top-2000
__global__ __launch_bounds__(256) void rank_kernel(
    const int* __restrict__ candCnt, const int* __restrict__ candIdx,
    const double* __restrict__ candKey, const double* __restrict__ boxes,
    int* __restrict__ topIdx, int* __restrict__ topValid, double* __restrict__ bsel)
{
    __shared__ double sk[256];
    __shared__ int si[256];
    int img = blockIdx.y, t = threadIdx.x;
    int M = candCnt[img];
    if (blockIdx.x * 256 >= M) return;   // uniform per block
    int i = blockIdx.x * 256 + t;
    bool act = i < M;
    double ki = 0.0; int pi = 0;
    if (act) { ki = candKey[(size_t)img * NPOS + i]; pi = candIdx[img * NPOS + i]; }
    int rank = 0;
    for (int jb = 0; jb < M; jb += 256) {
        int j = jb + t;
        if (j < M) { sk[t] = candKey[(size_t)img * NPOS + j]; si[t] = candIdx[img * NPOS + j]; }
        __syncthreads();
        int lim = min(256, M - jb);
        if (act) {
            for (int jj = 0; jj < lim; ++jj) {
                double kj = sk[jj]; int pj = si[jj];
                rank += (kj > ki || (kj == ki && pj < pi)) ? 1 : 0;
            }
        }
        __syncthreads();
    }
    if (act && rank < PRE) {
        topIdx[img * PRE + rank] = pi;
        topValid[img * PRE + rank] = (ki != -INFINITY) ? 1 : 0;
        const double* bp = &boxes[((size_t)img * NPOS + pi) * 4];
        double* bs = &bsel[((size_t)img * PRE + rank) * 4];
        bs[0] = bp[0]; bs[1] = bp[1]; bs[2] = bp[2]; bs[3] = bp[3];
    }
}

// grid (2000, 4): per-row suppression bitmask (j > i, iou > 0.7)
__global__ __launch_bounds__(256) void mask_kernel(
    const double* __restrict__ bsel, unsigned long long* __restrict__ mask)
{
    int i = blockIdx.x, img = blockIdx.y, t = threadIdx.x;
    const double* bi = &bsel[((size_t)img * PRE + i) * 4];
    double y1i = bi[0], x1i = bi[1], y2i = bi[2], x2i = bi[3];
    double ai = (y2i - y1i) * (x2i - x1i);
#pragma unroll 1
    for (int it = 0; it < 8; ++it) {
        int j = it * 256 + t;
        bool pred = false;
        if (j < PRE && j > i) {
            const double* bj = &bsel[((size_t)img * PRE + j) * 4];
            double ty = fmax(y1i, bj[0]), tx = fmax(x1i, bj[1]);
            double by = fmin(y2i, bj[2]), bx = fmin(x2i, bj[3]);
            double inter = fmax(by - ty, 0.0) * fmax(bx - tx, 0.0);
            double aj = (bj[2] - bj[0]) * (bj[3] - bj[1]);
            double iou = inter / (ai + aj - inter);
            pred = iou > 0.7;
        }
        unsigned long long m = __ballot(pred);
        if ((t & 63) == 0)
            mask[((size_t)img * PRE + i) * 32 + it * 4 + (t >> 6)] = m;
    }
}

// grid 4 x 64 thr (1 wave): sequential greedy NMS over 2000 with bitmask words
__global__ void nms_kernel(const unsigned long long* __restrict__ mask,
                           const int* __restrict__ topValid, int* __restrict__ keepA)
{
    int img = blockIdx.x, lane = threadIdx.x;
    size_t base = (size_t)img * PRE;
    unsigned long long remv = 0;
    if (lane < 32) {
        unsigned long long tv = 0;
        for (int b = 0; b < 64; ++b) {
            int idx = lane * 64 + b;
            if (idx < PRE && topValid[base + idx]) tv |= (1ull << b);
        }
        remv = ~tv;   // invalid (-inf) entries pre-suppressed
    }
    const unsigned long long* mrow = &mask[base * 32];
    unsigned long long c0 = 0, c1 = 0, c2 = 0, c3 = 0;
    if (lane < 32) {
        c0 = mrow[(size_t)0 * 32 + lane]; c1 = mrow[(size_t)1 * 32 + lane];
        c2 = mrow[(size_t)2 * 32 + lane]; c3 = mrow[(size_t)3 * 32 + lane];
    }
    for (int i = 0; i < PRE; i += 4) {
        unsigned long long n0 = 0, n1 = 0, n2 = 0, n3 = 0;
        if (lane < 32 && i + 4 < PRE) {
            n0 = mrow[(size_t)(i + 4) * 32 + lane];
            n1 = mrow[(size_t)(i + 5) * 32 + lane];
            n2 = mrow[(size_t)(i + 6) * 32 + lane];
            n3 = mrow[(size_t)(i + 7) * 32 + lane];
        }
        {
            unsigned long long rw = __shfl(remv, i >> 6);
            int kp = !((rw >> (i & 63)) & 1ull);
            if (lane == 0) keepA[base + i] = kp;
            if (kp) remv |= c0;
        }
        {
            int ii = i + 1;
            unsigned long long rw = __shfl(remv, ii >> 6);
            int kp = !((rw >> (ii & 63)) & 1ull);
            if (lane == 0) keepA[base + ii] = kp;
            if (kp) remv |= c1;
        }
        {
            int ii = i + 2;
            unsigned long long rw = __shfl(remv, ii >> 6);
            int kp = !((rw >> (ii & 63)) & 1ull);
            if (lane == 0) keepA[base + ii] = kp;
            if (kp) remv |= c2;
        }
        {
            int ii = i + 3;
            unsigned long long rw = __shfl(remv, ii >> 6);
            int kp = !((rw >> (ii & 63)) & 1ull);
            if (lane == 0) keepA[base + ii] = kp;
            if (kp) remv |= c3;
        }
        c0 = n0; c1 = n1; c2 = n2; c3 = n3;
    }
}

// grid 4 x 256: prefix-scan keep -> emit first 300 kept rois, zero the rest
__global__ __launch_bounds__(256) void final_kernel(
    const int* __restrict__ keepA, const double* __restrict__ bsel, float* __restrict__ out)
{
    __shared__ int ssum[256];
    __shared__ int stot;
    int img = blockIdx.x, t = threadIdx.x;
    size_t base = (size_t)img * PRE;
    int loc[8]; int s = 0;
#pragma unroll
    for (int k = 0; k < 8; ++k) {
        int i = t * 8 + k;
        loc[k] = (i < PRE) ? keepA[base + i] : 0;
        s += loc[k];
    }
    ssum[t] = s;
    __syncthreads();
    if (t == 0) {
        int run = 0;
        for (int u = 0; u < 256; ++u) { int tmp = ssum[u]; ssum[u] = run; run += tmp; }
        stot = run;
    }
    __syncthreads();
    int run = ssum[t];
#pragma unroll
    for (int k = 0; k < 8; ++k) {
        int i = t * 8 + k;
        if (i < PRE && loc[k]) {
            int p = run++;
            if (p < POST) {
                const double* bp = &bsel[(base + i) * 4];
                size_t ro = ROISOFF + ((size_t)img * POST + p) * 4;
                out[ro + 0] = (float)bp[0]; out[ro + 1] = (float)bp[1];
                out[ro + 2] = (float)bp[2]; out[ro + 3] = (float)bp[3];
                out[RIDXOFF + img * POST + p] = (float)img;
            }
        }
    }
    __syncthreads();
    int nk = stot;
    for (int r = t; r < POST; r += 256) {
        if (r >= nk) {
            size_t ro = ROISOFF + ((size_t)img * POST + r) * 4;
            out[ro + 0] = 0.f; out[ro + 1] = 0.f; out[ro + 2] = 0.f; out[ro + 3] = 0.f;
            out[RIDXOFF + img * POST + r] = -1.f;
        }
    }
}

// ---------------------------------------------------------------------------
extern "C" void kernel_launch(void* const* d_in, const int* in_sizes, int n_in,
                              void* d_out, int out_size, void* d_ws, size_t ws_size,
                              hipStream_t stream)
{
    const float* x   = (const float*)d_in[0];
    const float* c1w = (const float*)d_in[1];
    const float* c1b = (const float*)d_in[2];
    const float* sw  = (const float*)d_in[3];
    const float* sb  = (const float*)d_in[4];
    const float* lw  = (const float*)d_in[5];
    const float* lb  = (const float*)d_in[6];
    const int*   ih  = (const int*)d_in[7];
    const int*   iw  = (const int*)d_in[8];
    float* out = (float*)d_out;
    (void)in_sizes; (void)n_in; (void)out_size; (void)ws_size;

    char* ws = (char*)d_ws;
    size_t off = 0;
    auto alloc = [&](size_t bytes) -> void* {
        void* p = (void*)(ws + off);
        off = (off + bytes + 255) & ~(size_t)255;
        return p;
    };
    double* hbuf     = (double*)alloc((size_t)KSPLIT * NIMG * CMID * 4096 * 8); // 134 MiB
    float*  wt32     = (float*) alloc((size_t)CMID * CIN * 9 * 4);              // 18.9 MiB
    double* locws    = (double*)alloc((size_t)NIMG * NPOS * 4 * 8);
    double* keyws    = (double*)alloc((size_t)NIMG * NPOS * 8);
    double* boxes    = (double*)alloc((size_t)NIMG * NPOS * 4 * 8);
    unsigned* hist   = (unsigned*)alloc((size_t)NIMG * 4096 * 4);
    int*    cutoffb  = (int*)   alloc(64);
    int*    candCnt  = (int*)   alloc(64);
    int*    candIdx  = (int*)   alloc((size_t)NIMG * NPOS * 4);
    double* candKey  = (double*)alloc((size_t)NIMG * NPOS * 8);
    int*    topIdx   = (int*)   alloc((size_t)NIMG * PRE * 4);
    int*    topValid = (int*)   alloc((size_t)NIMG * PRE * 4);
    double* bsel     = (double*)alloc((size_t)NIMG * PRE * 4 * 8);
    unsigned long long* mask = (unsigned long long*)alloc((size_t)NIMG * PRE * 32 * 8);
    int*    keepA    = (int*)   alloc((size_t)NIMG * PRE * 4);

    hipMemsetAsync(hist, 0, (size_t)NIMG * 4096 * 4, stream);
    hipMemsetAsync(candCnt, 0, 64, stream);

    wtrans_kernel <<<dim3(144, 8),                256, 0, stream>>>(c1w, wt32);
    conv1_kernel  <<<dim3(16, 16, NIMG * KSPLIT), 256, 0, stream>>>(x, wt32, hbuf);
    conv1x1_kernel<<<dim3(16, 4, NIMG),           256, 0, stream>>>(hbuf, c1b, sw, sb, lw, lb,
                                                                    out, locws, keyws);
    boxes_kernel  <<<dim3(144, NIMG),             256, 0, stream>>>(keyws, locws, ih, iw, out, boxes, hist);
    cutoff_kernel <<<NIMG, 64, 0, stream>>>(hist, cutoffb);
    compact_kernel<<<dim3(144, NIMG),             256, 0, stream>>>(keyws, cutoffb, candCnt, candIdx, candKey);
    rank_kernel   <<<dim3(144, NIMG),             256, 0, stream>>>(candCnt, candIdx, candKey, boxes,
                                                                    topIdx, topValid, bsel);
    mask_kernel   <<<dim3(PRE, NIMG),             256, 0, stream>>>(bsel, mask);
    nms_kernel    <<<NIMG, 64, 0, stream>>>(mask, topValid, keepA);
    final_kernel  <<<NIMG, 256, 0, stream>>>(keepA, bsel, out);
}